// Round 4
// baseline (698.599 us; speedup 1.0000x reference)
//
#include <hip/hip_runtime.h>
#include <stdint.h>

// Problem (fp32 in / fp32 out): out = relu((x + (x@Wv^T+bv)@Wo^T + bo) @ Wn^T + bn)
//   softmax over a single score == 1 -> q,k path is dead code.
// Reformulated: out = relu(x@Wn^T + v@Wm^T + biasTot)
//   v  = x@Wv^T + bv          [8192 x 64]
//   Wm = Wn @ Wo              [4096 x 64]
//   biasTot = bn + Wn @ bo    [4096]
// Round 8: RESUBMIT of round-7 (container failed twice = infra flake; no
//   dispatch data was produced). Design audit found no correctness/hang risk.
//   - ONE aux dispatch (k_pre): V/Wm/biasTot blocks read ORIGINAL fp32 inputs
//     (reg-staged in-register cvt to bf16 in LDS) -> no dependency on cvt
//     blocks -> fused. Wvb/WoT workspace buffers eliminated.
//   - Long-pole GEMM/bias blocks at lowest block ids (dispatch first, overlap
//     the BW-bound cvt sweep).
//   - k_main: round-4 structure verbatim (proven 268.6us), plain tile map.

typedef unsigned short u16;
typedef float f32x4 __attribute__((ext_vector_type(4)));
typedef __bf16 bf16x8 __attribute__((ext_vector_type(8)));
typedef u16 u16x8 __attribute__((ext_vector_type(8)));

__device__ __forceinline__ float b2f(u16 u) {
  union { unsigned int i; float f; } x; x.i = ((unsigned int)u) << 16; return x.f;
}
__device__ __forceinline__ u16 f2b(float f) {  // round-to-nearest-even
  union { float f; unsigned int i; } x; x.f = f;
  unsigned int r = x.i + 0x7FFFu + ((x.i >> 16) & 1u);
  return (u16)(r >> 16);
}

// async global->LDS, 16B per lane; lds base wave-uniform (lane lands at base + lane*16B)
__device__ __forceinline__ void gl_lds16(const u16* g, u16* l) {
#if __has_builtin(__builtin_amdgcn_global_load_lds)
  __builtin_amdgcn_global_load_lds((__attribute__((address_space(1))) void*)g,
                                   (__attribute__((address_space(3))) void*)l, 16, 0, 0);
#else
  int lane = threadIdx.x & 63;
  *(u16x8*)(l + lane * 8) = *(const u16x8*)g;
#endif
}

__device__ __forceinline__ f32x4 mfma16(bf16x8 a, bf16x8 b, f32x4 c) {
  return __builtin_amdgcn_mfma_f32_16x16x32_bf16(a, b, c, 0, 0, 0);
}

#define PBK 128

// ---------------------------------------------------------------------------
// gemm_n64_f32: C[M,64](bf16) = bf16(A_f32) @ bf16(B_f32)^T  (+bias), K=4096.
//   Same LDS layout / swizzle / MFMA loop as the proven gemm_n64; only the
//   staging differs: fp32 global loads + in-register cvt + ds_write_b128.
//   BT=false: B is [64][4096] row-major (Wv).
//   BT=true : B element [a][k] = Bsrc[k*64 + a]  (Wo [4096][64] transposed).
// ---------------------------------------------------------------------------
template <bool BT>
__device__ void gemm_n64_f32(const float* __restrict__ A, const float* __restrict__ B,
                             u16* __restrict__ C, const float* __restrict__ bias,
                             long m0, u16* lA, u16* lB) {
  const int tid = threadIdx.x;
  const int w = tid >> 6, l = tid & 63;
  const int rg = l >> 4;   // row within 4-row group
  const int sl = l & 15;   // LDS 16B-slot
  f32x4 acc[4];
#pragma unroll
  for (int nt = 0; nt < 4; ++nt) acc[nt] = (f32x4)(0.f);

  for (int k0 = 0; k0 < 4096; k0 += PBK) {
    __syncthreads();
#pragma unroll
    for (int i = 0; i < 4; ++i) {
      int row = w * 16 + i * 4 + rg;
      int p = sl ^ (i * 4 + rg);          // swizzled global 16B-slot
      // A stage: contiguous fp32
      const float* ga = &A[(m0 + row) * 4096L + k0 + p * 8];
      f32x4 a0 = *(const f32x4*)ga;
      f32x4 a1 = *(const f32x4*)(ga + 4);
      u16x8 av;
#pragma unroll
      for (int e = 0; e < 4; ++e) { av[e] = f2b(a0[e]); av[4 + e] = f2b(a1[e]); }
      *(u16x8*)&lA[(w * 16 + i * 4) * PBK + l * 8] = av;
      // B stage
      u16x8 bv;
      if (!BT) {
        const float* gb = &B[(long)row * 4096 + k0 + p * 8];
        f32x4 b0 = *(const f32x4*)gb;
        f32x4 b1 = *(const f32x4*)(gb + 4);
#pragma unroll
        for (int e = 0; e < 4; ++e) { bv[e] = f2b(b0[e]); bv[4 + e] = f2b(b1[e]); }
      } else {
        const float* gb = &B[(long)(k0 + p * 8) * 64 + row];
#pragma unroll
        for (int e = 0; e < 8; ++e) bv[e] = f2b(gb[e * 64]);
      }
      *(u16x8*)&lB[(w * 16 + i * 4) * PBK + l * 8] = bv;
    }
    __syncthreads();
#pragma unroll
    for (int kk = 0; kk < 4; ++kk) {
      int slotA = ((kk * 4 + (l >> 4)) ^ (l & 15)) * 8;
      bf16x8 af = *(const bf16x8*)&lA[(w * 16 + (l & 15)) * PBK + slotA];
#pragma unroll
      for (int nt = 0; nt < 4; ++nt) {
        bf16x8 bf = *(const bf16x8*)&lB[(nt * 16 + (l & 15)) * PBK + slotA];
        acc[nt] = mfma16(af, bf, acc[nt]);
      }
    }
  }
#pragma unroll
  for (int nt = 0; nt < 4; ++nt) {
    int col = nt * 16 + (l & 15);
    float bb = bias ? bias[col] : 0.f;
#pragma unroll
    for (int r = 0; r < 4; ++r) {
      long row = m0 + w * 16 + (l >> 4) * 4 + r;
      C[row * 64 + col] = f2b(acc[nt][r] + bb);
    }
  }
}

// ---------------------------------------------------------------------------
// k_pre: ONE dispatch, all aux work, all blocks independent (fp32 sources):
//   [0,128)      V = x@Wv^T + bv          (MFMA, reg-staged fp32->bf16)
//   [128,192)    Wm = Wn@Wo               (MFMA, B transpose-read from Wo)
//   [192,1216)   biasTot = bn + Wn@bo     (fp32 dot, wave/row)
//   [1216,25792) cvt: xb = bf16(x), Wnb = bf16(Wn)   (8 elems/thread)
// Long-pole blocks first -> overlap with the BW-bound cvt sweep.
// ---------------------------------------------------------------------------
#define XCH 4194304L    // 33554432/8  (x groups)
#define WNCH 2097152L   // 16777216/8  (Wn groups)
#define AUXB 1216       // non-cvt blocks
__global__ __launch_bounds__(256) void k_pre(
    const float* __restrict__ x, const float* __restrict__ Wn,
    const float* __restrict__ Wv, const float* __restrict__ Wo,
    const float* __restrict__ bv, const float* __restrict__ bo, const float* __restrict__ bn,
    u16* __restrict__ xb, u16* __restrict__ Wnb,
    u16* __restrict__ V, u16* __restrict__ Wm, float* __restrict__ biasTot) {
  __shared__ __align__(16) u16 lA[64 * PBK];
  __shared__ __align__(16) u16 lB[64 * PBK];
  const int bid = blockIdx.x;
  if (bid < 128) {
    gemm_n64_f32<false>(x, Wv, V, bv, (long)bid * 64, lA, lB);
  } else if (bid < 192) {
    gemm_n64_f32<true>(Wn, Wo, Wm, nullptr, (long)(bid - 128) * 64, lA, lB);
  } else if (bid < AUXB) {
    const int w = threadIdx.x >> 6, l = threadIdx.x & 63;
    const int n = (bid - 192) * 4 + w;
    float s = 0.f;
#pragma unroll
    for (int j = 0; j < 8; ++j) {
      int off = (j * 64 + l) * 8;
      f32x4 a0 = *(const f32x4*)&Wn[(size_t)n * 4096 + off];
      f32x4 a1 = *(const f32x4*)&Wn[(size_t)n * 4096 + off + 4];
      f32x4 c0 = *(const f32x4*)&bo[off];
      f32x4 c1 = *(const f32x4*)&bo[off + 4];
#pragma unroll
      for (int e = 0; e < 4; ++e) s += a0[e] * c0[e] + a1[e] * c1[e];
    }
#pragma unroll
    for (int o = 32; o > 0; o >>= 1) s += __shfl_xor(s, o, 64);
    if (l == 0) biasTot[n] = s + bn[n];
  } else {
    long i = (long)(bid - AUXB) * 256 + threadIdx.x;
    const float* src; u16* dst; long off;
    if (i < XCH) { src = x; dst = xb; off = i * 8; }
    else { src = Wn; dst = Wnb; off = (i - XCH) * 8; }
    f32x4 a = *(const f32x4*)&src[off];
    f32x4 b = *(const f32x4*)&src[off + 4];
    u16x8 o;
#pragma unroll
    for (int e = 0; e < 4; ++e) { o[e] = f2b(a[e]); o[4 + e] = f2b(b[e]); }
    *(u16x8*)&dst[off] = o;
  }
}

// ---------------------------------------------------------------------------
// k_main (round-4 structure, proven 268.6us): BK=64, XOR-swizzled LDS (128B
//   rows), 64 main iters + 1 tail iter (V/Wm, K=64). 128x128 tile, 4 waves
//   2x2, gl_lds16 staging, fp32 out via per-wave LDS transpose. LDS 32 KB.
//   Plain bid->tile mapping (XCD swizzle reverted: FETCH dropped but dur
//   flat/worse in round-6 A/B).
// ---------------------------------------------------------------------------
__global__ __launch_bounds__(256, 2) void k_main(
    const u16* __restrict__ X, const u16* __restrict__ Wn,
    const u16* __restrict__ V, const u16* __restrict__ Wm,
    const float* __restrict__ biasTot, float* __restrict__ Out) {
  __shared__ __align__(16) u16 smem[2 * 128 * 64];  // 32 KB
  u16* lA = smem;
  u16* lB = smem + 128 * 64;
  const int tid = threadIdx.x;
  const int w = tid >> 6, l = tid & 63;
  const int wRow = (w & 1) * 64, wCol = (w >> 1) * 64;
  const long mBase = (long)(blockIdx.x >> 5) * 128;
  const int nBase = (int)(blockIdx.x & 31) * 128;

  f32x4 acc[4][4];
#pragma unroll
  for (int mt = 0; mt < 4; ++mt)
#pragma unroll
    for (int nt = 0; nt < 4; ++nt) acc[mt][nt] = (f32x4)(0.f);

  const int srow = l >> 3;              // staging sub-row 0..7
  const int sp = ((l & 7) ^ srow) * 8;  // swizzled global 16B-slot (elements)

  for (int kb = 0; kb < 65; ++kb) {
    const u16 *pA, *pB; long lda;
    if (kb < 64) { pA = X + (long)kb * 64; pB = Wn + (long)kb * 64; lda = 4096; }
    else         { pA = V;                 pB = Wm;                 lda = 64;  }
    __syncthreads();
#pragma unroll
    for (int i = 0; i < 4; ++i) {
      int row = w * 32 + i * 8 + srow;
      gl_lds16(pA + (mBase + row) * lda + sp, lA + (w * 32 + i * 8) * 64);
      gl_lds16(pB + (long)(nBase + row) * lda + sp, lB + (w * 32 + i * 8) * 64);
    }
    __syncthreads();
#pragma unroll
    for (int kk = 0; kk < 2; ++kk) {
      int slot = ((kk * 4 + (l >> 4)) ^ (l & 7)) * 8;
      bf16x8 af[4], bfr[4];
#pragma unroll
      for (int mt = 0; mt < 4; ++mt)
        af[mt] = *(const bf16x8*)&lA[(wRow + mt * 16 + (l & 15)) * 64 + slot];
#pragma unroll
      for (int nt = 0; nt < 4; ++nt)
        bfr[nt] = *(const bf16x8*)&lB[(wCol + nt * 16 + (l & 15)) * 64 + slot];
#pragma unroll
      for (int mt = 0; mt < 4; ++mt)
#pragma unroll
        for (int nt = 0; nt < 4; ++nt) acc[mt][nt] = mfma16(af[mt], bfr[nt], acc[mt][nt]);
    }
  }

  // epilogue: bias + relu, fp32; per-wave LDS transpose (4 KB/wave), dwordx4 stores
  __syncthreads();
  float* eb = ((float*)smem) + w * 1024;
#pragma unroll
  for (int mt = 0; mt < 4; ++mt) {
#pragma unroll
    for (int nt = 0; nt < 4; ++nt) {
      float bt = biasTot[nBase + wCol + nt * 16 + (l & 15)];
#pragma unroll
      for (int r = 0; r < 4; ++r) {
        float val = acc[mt][nt][r] + bt;
        eb[((l >> 4) * 4 + r) * 64 + nt * 16 + (l & 15)] = fmaxf(val, 0.f);
      }
    }
    int rr = l >> 2, c0 = (l & 3) * 16;
    long grow = mBase + wRow + mt * 16 + rr;
    int gcol = nBase + wCol + c0;
    f32x4 o0 = *(const f32x4*)&eb[rr * 64 + c0];
    f32x4 o1 = *(const f32x4*)&eb[rr * 64 + c0 + 4];
    f32x4 o2 = *(const f32x4*)&eb[rr * 64 + c0 + 8];
    f32x4 o3 = *(const f32x4*)&eb[rr * 64 + c0 + 12];
    *(f32x4*)&Out[grow * 4096 + gcol] = o0;
    *(f32x4*)&Out[grow * 4096 + gcol + 4] = o1;
    *(f32x4*)&Out[grow * 4096 + gcol + 8] = o2;
    *(f32x4*)&Out[grow * 4096 + gcol + 12] = o3;
  }
}

// ---------------------------------------------------------------------------
extern "C" void kernel_launch(void* const* d_in, const int* in_sizes, int n_in,
                              void* d_out, int out_size, void* d_ws, size_t ws_size,
                              hipStream_t stream) {
  const float* x  = (const float*)d_in[0];
  const float* Wv = (const float*)d_in[5];
  const float* bv = (const float*)d_in[6];
  const float* Wo = (const float*)d_in[7];
  const float* bo = (const float*)d_in[8];
  const float* Wn = (const float*)d_in[9];
  const float* bn = (const float*)d_in[10];
  float* out = (float*)d_out;

  char* ws = (char*)d_ws;
  u16* xb  = (u16*)ws;                             // 8192*4096*2 = 64 MB
  u16* Wnb = (u16*)(ws + (64L << 20));             // 4096*4096*2 = 32 MB
  u16* V   = (u16*)(ws + (96L << 20));             // 8192*64*2   = 1 MB
  u16* Wm  = (u16*)(ws + (97L << 20));             // 4096*64*2   = 512 KB
  float* biasTot = (float*)(ws + (97L << 20) + (512 << 10));  // 16 KB

  k_pre<<<dim3(AUXB + 24576), dim3(256), 0, stream>>>(
      x, Wn, Wv, Wo, bv, bo, bn, xb, Wnb, V, Wm, biasTot);
  k_main<<<dim3(2048), dim3(256), 0, stream>>>(xb, Wnb, V, Wm, biasTot, out);
}

// Round 5
// 667.839 us; speedup vs baseline: 1.0461x; 1.0461x over previous
//
#include <hip/hip_runtime.h>
#include <stdint.h>

// Problem (fp32 in / fp32 out): out = relu((x + (x@Wv^T+bv)@Wo^T + bo) @ Wn^T + bn)
//   softmax over a single score == 1 -> q,k path is dead code.
// Reformulated: out = relu(x@Wn^T + v@Wm^T + biasTot)
//   v  = x@Wv^T + bv          [8192 x 64]
//   Wm = Wn @ Wo              [4096 x 64]
//   biasTot = bn + Wn @ bo    [4096]
// Round 9: FULL REVERT to round-0 pipeline (best measured: 586.8us total,
//   k_main 268.6) -- round-8's fused aux regressed (VGPR coupling starved the
//   BW-bound cvt sweep of occupancy).
// ONE k_main change: N-OUTER XCD-chunked tile mapping. Theory: k_main is
//   L3-BW-bound (~4GB panel reads / 268us = 15 TB/s; per-XCD concurrent
//   working set >> 4MB L2 under plain mapping). Each XCD owns 4 contiguous
//   n-tiles, m innermost -> ~2 concurrent B-panels/XCD (2MB, L2-fits) ->
//   B reads become L2 hits, L3 traffic halves (A only).
//   (Round-6's m-chunked swizzle left 12 B-panels/XCD -> L2 thrash -> flat.)

typedef unsigned short u16;
typedef float f32x4 __attribute__((ext_vector_type(4)));
typedef __bf16 bf16x8 __attribute__((ext_vector_type(8)));
typedef u16 u16x8 __attribute__((ext_vector_type(8)));

__device__ __forceinline__ float b2f(u16 u) {
  union { unsigned int i; float f; } x; x.i = ((unsigned int)u) << 16; return x.f;
}
__device__ __forceinline__ u16 f2b(float f) {  // round-to-nearest-even
  union { float f; unsigned int i; } x; x.f = f;
  unsigned int r = x.i + 0x7FFFu + ((x.i >> 16) & 1u);
  return (u16)(r >> 16);
}

// async global->LDS, 16B per lane; lds base wave-uniform (lane lands at base + lane*16B)
__device__ __forceinline__ void gl_lds16(const u16* g, u16* l) {
#if __has_builtin(__builtin_amdgcn_global_load_lds)
  __builtin_amdgcn_global_load_lds((__attribute__((address_space(1))) void*)g,
                                   (__attribute__((address_space(3))) void*)l, 16, 0, 0);
#else
  int lane = threadIdx.x & 63;
  *(u16x8*)(l + lane * 8) = *(const u16x8*)g;
#endif
}

__device__ __forceinline__ f32x4 mfma16(bf16x8 a, bf16x8 b, f32x4 c) {
  return __builtin_amdgcn_mfma_f32_16x16x32_bf16(a, b, c, 0, 0, 0);
}

// ---------------------------------------------------------------------------
// k_cvt: fp32 -> bf16 for x (33.5M), Wn (16.7M), Wv (262K). 8 floats/thread.
// (identical to round 0)
// ---------------------------------------------------------------------------
#define XCH 4194304L   // 33554432/8
#define WNCH 2097152L  // 16777216/8
__global__ __launch_bounds__(256) void k_cvt(
    const float* __restrict__ x, const float* __restrict__ Wn, const float* __restrict__ Wv,
    u16* __restrict__ xb, u16* __restrict__ Wnb, u16* __restrict__ Wvb) {
  long i = (long)blockIdx.x * 256 + threadIdx.x;
  const float* src; u16* dst; long off;
  if (i < XCH) { src = x; dst = xb; off = i * 8; }
  else if (i < XCH + WNCH) { src = Wn; dst = Wnb; off = (i - XCH) * 8; }
  else { src = Wv; dst = Wvb; off = (i - XCH - WNCH) * 8; }
  f32x4 a = *(const f32x4*)&src[off];
  f32x4 b = *(const f32x4*)&src[off + 4];
  u16x8 o;
#pragma unroll
  for (int e = 0; e < 4; ++e) { o[e] = f2b(a[e]); o[4 + e] = f2b(b[e]); }
  *(u16x8*)&dst[off] = o;
}

// ---------------------------------------------------------------------------
// kT: WoT[a][k] = bf16(Wo[k][a])  (identical to round 0)
// ---------------------------------------------------------------------------
__global__ __launch_bounds__(256) void kT(const float* __restrict__ Wo, u16* __restrict__ WoT) {
  __shared__ __align__(16) u16 t[64 * 72];
  const int b = blockIdx.x;
  const int tid = threadIdx.x;
  {
    int k = tid >> 2, a0 = (tid & 3) * 16;
    const float* src = &Wo[(size_t)(b * 64 + k) * 64 + a0];
#pragma unroll
    for (int q = 0; q < 4; ++q) {
      f32x4 v = *(const f32x4*)&src[q * 4];
#pragma unroll
      for (int e = 0; e < 4; ++e) t[k * 72 + a0 + q * 4 + e] = f2b(v[e]);
    }
  }
  __syncthreads();
  {
    int a = tid >> 2, k0 = (tid & 3) * 16;
    u16x8 o0, o1;
#pragma unroll
    for (int j = 0; j < 8; ++j) o0[j] = t[(k0 + j) * 72 + a];
#pragma unroll
    for (int j = 0; j < 8; ++j) o1[j] = t[(k0 + 8 + j) * 72 + a];
    *(u16x8*)&WoT[(size_t)a * 4096 + b * 64 + k0] = o0;
    *(u16x8*)&WoT[(size_t)a * 4096 + b * 64 + k0 + 8] = o1;
  }
}

// ---------------------------------------------------------------------------
// gemm_n64 (identical to round 0)
// ---------------------------------------------------------------------------
#define PBK 128
__device__ void gemm_n64(const u16* __restrict__ A, const u16* __restrict__ B,
                         u16* __restrict__ C, const float* __restrict__ bias,
                         long m0, u16* lA, u16* lB) {
  const int tid = threadIdx.x;
  const int w = tid >> 6, l = tid & 63;
  f32x4 acc[4];
#pragma unroll
  for (int nt = 0; nt < 4; ++nt) acc[nt] = (f32x4)(0.f);

  for (int k0 = 0; k0 < 4096; k0 += PBK) {
    __syncthreads();
#pragma unroll
    for (int i = 0; i < 4; ++i) {
      int row = w * 16 + i * 4 + (l >> 4);
      int p = (l & 15) ^ (i * 4 + (l >> 4));
      gl_lds16(A + (m0 + row) * (long)4096 + k0 + p * 8, lA + (w * 16 + i * 4) * PBK);
      gl_lds16(B + (long)row * 4096 + k0 + p * 8, lB + (w * 16 + i * 4) * PBK);
    }
    __syncthreads();
#pragma unroll
    for (int kk = 0; kk < 4; ++kk) {
      int slotA = ((kk * 4 + (l >> 4)) ^ (l & 15)) * 8;
      bf16x8 af = *(const bf16x8*)&lA[(w * 16 + (l & 15)) * PBK + slotA];
#pragma unroll
      for (int nt = 0; nt < 4; ++nt) {
        bf16x8 bf = *(const bf16x8*)&lB[(nt * 16 + (l & 15)) * PBK + slotA];
        acc[nt] = mfma16(af, bf, acc[nt]);
      }
    }
  }
#pragma unroll
  for (int nt = 0; nt < 4; ++nt) {
    int col = nt * 16 + (l & 15);
    float bb = bias ? bias[col] : 0.f;
#pragma unroll
    for (int r = 0; r < 4; ++r) {
      long row = m0 + w * 16 + (l >> 4) * 4 + r;
      C[row * 64 + col] = f2b(acc[nt][r] + bb);
    }
  }
}

// ---------------------------------------------------------------------------
// k_prep (identical to round 0)
// ---------------------------------------------------------------------------
__global__ __launch_bounds__(256, 2) void k_prep(
    const u16* __restrict__ xb, const u16* __restrict__ Wvb, const float* __restrict__ bv,
    const u16* __restrict__ Wnb, const u16* __restrict__ WoT,
    const float* __restrict__ bo, const float* __restrict__ bn,
    u16* __restrict__ V, u16* __restrict__ Wm, float* __restrict__ biasTot) {
  __shared__ __align__(16) u16 lA[64 * PBK];
  __shared__ __align__(16) u16 lB[64 * PBK];
  const int bid = blockIdx.x;
  if (bid < 128) {
    gemm_n64(xb, Wvb, V, bv, (long)bid * 64, lA, lB);
  } else if (bid < 192) {
    gemm_n64(Wnb, WoT, Wm, nullptr, (long)(bid - 128) * 64, lA, lB);
  } else {
    const int w = threadIdx.x >> 6, l = threadIdx.x & 63;
    const int n = (bid - 192) * 4 + w;
    float s = 0.f;
#pragma unroll
    for (int j = 0; j < 8; ++j) {
      int off = (j * 64 + l) * 8;
      u16x8 a = *(const u16x8*)&Wnb[(size_t)n * 4096 + off];
      f32x4 c0 = *(const f32x4*)&bo[off];
      f32x4 c1 = *(const f32x4*)&bo[off + 4];
#pragma unroll
      for (int e = 0; e < 4; ++e) s += b2f(a[e]) * c0[e] + b2f(a[4 + e]) * c1[e];
    }
#pragma unroll
    for (int o = 32; o > 0; o >>= 1) s += __shfl_xor(s, o, 64);
    if (l == 0) biasTot[n] = s + bn[n];
  }
}

// ---------------------------------------------------------------------------
// k_main (round-0 body, proven): BK=64, XOR-swizzled LDS slots, 65 iters
//   (64 X/Wn + 1 V/Wm tail), 128x128 tile, 4 waves 2x2, gl_lds16 staging,
//   fp32 out via per-wave LDS transpose. LDS 32 KB.
// ROUND-9 CHANGE (mapping only): N-outer XCD chunking.
//   xcd = bid&7 (round-robin dispatch), j = bid>>3 in [0,256)
//   nT = xcd*4 + (j>>6)   -- each XCD owns 4 contiguous n-tiles (B-panels)
//   mT = j&63             -- m innermost -> ~2 concurrent B-panels per XCD
//   => B-panel reads L2-hit; L3 serves A only (~2GB instead of ~4GB).
// ---------------------------------------------------------------------------
__global__ __launch_bounds__(256, 2) void k_main(
    const u16* __restrict__ X, const u16* __restrict__ Wn,
    const u16* __restrict__ V, const u16* __restrict__ Wm,
    const float* __restrict__ biasTot, float* __restrict__ Out) {
  __shared__ __align__(16) u16 smem[2 * 128 * 64];  // 32 KB
  u16* lA = smem;
  u16* lB = smem + 128 * 64;
  const int tid = threadIdx.x;
  const int w = tid >> 6, l = tid & 63;
  const int wRow = (w & 1) * 64, wCol = (w >> 1) * 64;
  const int xcd = (int)(blockIdx.x & 7);
  const int j   = (int)(blockIdx.x >> 3);   // 0..255 within XCD
  const int nT  = xcd * 4 + (j >> 6);       // 0..31, 4 per XCD
  const int mT  = j & 63;                   // m innermost
  const long mBase = (long)mT * 128;
  const int  nBase = nT * 128;

  f32x4 acc[4][4];
#pragma unroll
  for (int mt = 0; mt < 4; ++mt)
#pragma unroll
    for (int nt = 0; nt < 4; ++nt) acc[mt][nt] = (f32x4)(0.f);

  const int srow = l >> 3;              // staging sub-row 0..7
  const int sp = ((l & 7) ^ srow) * 8;  // swizzled global 16B-slot (elements)

  for (int kb = 0; kb < 65; ++kb) {
    const u16 *pA, *pB; long lda;
    if (kb < 64) { pA = X + (long)kb * 64; pB = Wn + (long)kb * 64; lda = 4096; }
    else         { pA = V;                 pB = Wm;                 lda = 64;  }
    __syncthreads();
#pragma unroll
    for (int i = 0; i < 4; ++i) {
      int row = w * 32 + i * 8 + srow;
      gl_lds16(pA + (mBase + row) * lda + sp, lA + (w * 32 + i * 8) * 64);
      gl_lds16(pB + (long)(nBase + row) * lda + sp, lB + (w * 32 + i * 8) * 64);
    }
    __syncthreads();
#pragma unroll
    for (int kk = 0; kk < 2; ++kk) {
      int slot = ((kk * 4 + (l >> 4)) ^ (l & 7)) * 8;
      bf16x8 af[4], bfr[4];
#pragma unroll
      for (int mt = 0; mt < 4; ++mt)
        af[mt] = *(const bf16x8*)&lA[(wRow + mt * 16 + (l & 15)) * 64 + slot];
#pragma unroll
      for (int nt = 0; nt < 4; ++nt)
        bfr[nt] = *(const bf16x8*)&lB[(wCol + nt * 16 + (l & 15)) * 64 + slot];
#pragma unroll
      for (int mt = 0; mt < 4; ++mt)
#pragma unroll
        for (int nt = 0; nt < 4; ++nt) acc[mt][nt] = mfma16(af[mt], bfr[nt], acc[mt][nt]);
    }
  }

  // epilogue: bias + relu, fp32; per-wave LDS transpose (4 KB/wave), dwordx4 stores
  __syncthreads();
  float* eb = ((float*)smem) + w * 1024;
#pragma unroll
  for (int mt = 0; mt < 4; ++mt) {
#pragma unroll
    for (int nt = 0; nt < 4; ++nt) {
      float bt = biasTot[nBase + wCol + nt * 16 + (l & 15)];
#pragma unroll
      for (int r = 0; r < 4; ++r) {
        float val = acc[mt][nt][r] + bt;
        eb[((l >> 4) * 4 + r) * 64 + nt * 16 + (l & 15)] = fmaxf(val, 0.f);
      }
    }
    int rr = l >> 2, c0 = (l & 3) * 16;
    long grow = mBase + wRow + mt * 16 + rr;
    int gcol = nBase + wCol + c0;
    f32x4 o0 = *(const f32x4*)&eb[rr * 64 + c0];
    f32x4 o1 = *(const f32x4*)&eb[rr * 64 + c0 + 4];
    f32x4 o2 = *(const f32x4*)&eb[rr * 64 + c0 + 8];
    f32x4 o3 = *(const f32x4*)&eb[rr * 64 + c0 + 12];
    *(f32x4*)&Out[grow * 4096 + gcol] = o0;
    *(f32x4*)&Out[grow * 4096 + gcol + 4] = o1;
    *(f32x4*)&Out[grow * 4096 + gcol + 8] = o2;
    *(f32x4*)&Out[grow * 4096 + gcol + 12] = o3;
  }
}

// ---------------------------------------------------------------------------
extern "C" void kernel_launch(void* const* d_in, const int* in_sizes, int n_in,
                              void* d_out, int out_size, void* d_ws, size_t ws_size,
                              hipStream_t stream) {
  const float* x  = (const float*)d_in[0];
  const float* Wv = (const float*)d_in[5];
  const float* bv = (const float*)d_in[6];
  const float* Wo = (const float*)d_in[7];
  const float* bo = (const float*)d_in[8];
  const float* Wn = (const float*)d_in[9];
  const float* bn = (const float*)d_in[10];
  float* out = (float*)d_out;

  char* ws = (char*)d_ws;
  u16* xb  = (u16*)ws;                             // 8192*4096*2 = 64 MB
  u16* Wnb = (u16*)(ws + (64L << 20));             // 4096*4096*2 = 32 MB
  u16* Wvb = (u16*)(ws + (96L << 20));             // 64*4096*2   = 512 KB
  u16* WoT = (u16*)(ws + (96L << 20) + (512 << 10));   // 512 KB
  u16* V   = (u16*)(ws + (97L << 20));             // 8192*64*2   = 1 MB
  u16* Wm  = (u16*)(ws + (98L << 20));             // 4096*64*2   = 512 KB
  float* biasTot = (float*)(ws + (98L << 20) + (512 << 10));  // 16 KB

  k_cvt<<<dim3(24704), dim3(256), 0, stream>>>(x, Wn, Wv, xb, Wnb, Wvb);
  kT<<<dim3(64), dim3(256), 0, stream>>>(Wo, WoT);
  k_prep<<<dim3(1216), dim3(256), 0, stream>>>(xb, Wvb, bv, Wnb, WoT, bo, bn, V, Wm, biasTot);
  k_main<<<dim3(2048), dim3(256), 0, stream>>>(xb, Wnb, V, Wm, biasTot, out);
}

// Round 6
// 608.689 us; speedup vs baseline: 1.1477x; 1.0972x over previous
//
#include <hip/hip_runtime.h>
#include <stdint.h>

// Problem (fp32 in / fp32 out): out = relu((x + (x@Wv^T+bv)@Wo^T + bo) @ Wn^T + bn)
//   softmax over a single score == 1 -> q,k path is dead code.
// Reformulated: out = relu(x@Wn^T + v@Wm^T + biasTot)
//   v  = x@Wv^T + bv          [8192 x 64]
//   Wm = Wn @ Wo              [4096 x 64]
//   biasTot = bn + Wn @ bo    [4096]
// Round 10: consolidate on round-0 (best measured 586.8us; nothing has beaten
//   it in 5 rounds). k_main mapping experiments CLOSED (plain best: m-chunk
//   flat, n-outer +27% w/ 2.6x FETCH). k_main + k_prep = round-0 EXACT.
// Aux trims only:
//   (1) k_cvt: grid-stride at 2048 blocks (32 waves/CU exactly) instead of
//       24704 one-shot blocks (G11 recipe for memory-bound ops).
//   (2) kT folded into k_cvt as 64 leading blocks (proven-safe fusion,
//       one fewer launch gap; WoT ready early for k_prep). 4 -> 3 dispatches.

typedef unsigned short u16;
typedef float f32x4 __attribute__((ext_vector_type(4)));
typedef __bf16 bf16x8 __attribute__((ext_vector_type(8)));
typedef u16 u16x8 __attribute__((ext_vector_type(8)));

__device__ __forceinline__ float b2f(u16 u) {
  union { unsigned int i; float f; } x; x.i = ((unsigned int)u) << 16; return x.f;
}
__device__ __forceinline__ u16 f2b(float f) {  // round-to-nearest-even
  union { float f; unsigned int i; } x; x.f = f;
  unsigned int r = x.i + 0x7FFFu + ((x.i >> 16) & 1u);
  return (u16)(r >> 16);
}

// async global->LDS, 16B per lane; lds base wave-uniform (lane lands at base + lane*16B)
__device__ __forceinline__ void gl_lds16(const u16* g, u16* l) {
#if __has_builtin(__builtin_amdgcn_global_load_lds)
  __builtin_amdgcn_global_load_lds((__attribute__((address_space(1))) void*)g,
                                   (__attribute__((address_space(3))) void*)l, 16, 0, 0);
#else
  int lane = threadIdx.x & 63;
  *(u16x8*)(l + lane * 8) = *(const u16x8*)g;
#endif
}

__device__ __forceinline__ f32x4 mfma16(bf16x8 a, bf16x8 b, f32x4 c) {
  return __builtin_amdgcn_mfma_f32_16x16x32_bf16(a, b, c, 0, 0, 0);
}

// ---------------------------------------------------------------------------
// k_cvt: blocks [0,64):   WoT[a][k] = bf16(Wo[k][a])  (kT body, round-0)
//        blocks [64,2112): grid-stride fp32->bf16 cvt for x, Wn, Wv
//        (8 floats/thread/iter; 2048 cvt blocks = 32 waves/CU exactly)
// ---------------------------------------------------------------------------
#define XCH 4194304L   // 33554432/8  (x 8-elem groups)
#define WNCH 2097152L  // 16777216/8  (Wn groups)
#define TOTG 6324224L  // + 32768 Wv groups
__global__ __launch_bounds__(256) void k_cvt(
    const float* __restrict__ x, const float* __restrict__ Wn,
    const float* __restrict__ Wv, const float* __restrict__ Wo,
    u16* __restrict__ xb, u16* __restrict__ Wnb, u16* __restrict__ Wvb,
    u16* __restrict__ WoT) {
  __shared__ __align__(16) u16 t[64 * 72];
  if (blockIdx.x < 64) {
    const int b = blockIdx.x;
    const int tid = threadIdx.x;
    {
      int k = tid >> 2, a0 = (tid & 3) * 16;
      const float* src = &Wo[(size_t)(b * 64 + k) * 64 + a0];
#pragma unroll
      for (int q = 0; q < 4; ++q) {
        f32x4 v = *(const f32x4*)&src[q * 4];
#pragma unroll
        for (int e = 0; e < 4; ++e) t[k * 72 + a0 + q * 4 + e] = f2b(v[e]);
      }
    }
    __syncthreads();
    {
      int a = tid >> 2, k0 = (tid & 3) * 16;
      u16x8 o0, o1;
#pragma unroll
      for (int j = 0; j < 8; ++j) o0[j] = t[(k0 + j) * 72 + a];
#pragma unroll
      for (int j = 0; j < 8; ++j) o1[j] = t[(k0 + 8 + j) * 72 + a];
      *(u16x8*)&WoT[(size_t)a * 4096 + b * 64 + k0] = o0;
      *(u16x8*)&WoT[(size_t)a * 4096 + b * 64 + k0 + 8] = o1;
    }
    return;
  }
  long i = (long)(blockIdx.x - 64) * 256 + threadIdx.x;
  const long stride = 2048L * 256;
  for (; i < TOTG; i += stride) {
    const float* src; u16* dst; long off;
    if (i < XCH) { src = x; dst = xb; off = i * 8; }
    else if (i < XCH + WNCH) { src = Wn; dst = Wnb; off = (i - XCH) * 8; }
    else { src = Wv; dst = Wvb; off = (i - XCH - WNCH) * 8; }
    f32x4 a = *(const f32x4*)&src[off];
    f32x4 b = *(const f32x4*)&src[off + 4];
    u16x8 o;
#pragma unroll
    for (int e = 0; e < 4; ++e) { o[e] = f2b(a[e]); o[4 + e] = f2b(b[e]); }
    *(u16x8*)&dst[off] = o;
  }
}

// ---------------------------------------------------------------------------
// gemm_n64 (identical to round 0)
// ---------------------------------------------------------------------------
#define PBK 128
__device__ void gemm_n64(const u16* __restrict__ A, const u16* __restrict__ B,
                         u16* __restrict__ C, const float* __restrict__ bias,
                         long m0, u16* lA, u16* lB) {
  const int tid = threadIdx.x;
  const int w = tid >> 6, l = tid & 63;
  f32x4 acc[4];
#pragma unroll
  for (int nt = 0; nt < 4; ++nt) acc[nt] = (f32x4)(0.f);

  for (int k0 = 0; k0 < 4096; k0 += PBK) {
    __syncthreads();
#pragma unroll
    for (int i = 0; i < 4; ++i) {
      int row = w * 16 + i * 4 + (l >> 4);
      int p = (l & 15) ^ (i * 4 + (l >> 4));
      gl_lds16(A + (m0 + row) * (long)4096 + k0 + p * 8, lA + (w * 16 + i * 4) * PBK);
      gl_lds16(B + (long)row * 4096 + k0 + p * 8, lB + (w * 16 + i * 4) * PBK);
    }
    __syncthreads();
#pragma unroll
    for (int kk = 0; kk < 4; ++kk) {
      int slotA = ((kk * 4 + (l >> 4)) ^ (l & 15)) * 8;
      bf16x8 af = *(const bf16x8*)&lA[(w * 16 + (l & 15)) * PBK + slotA];
#pragma unroll
      for (int nt = 0; nt < 4; ++nt) {
        bf16x8 bf = *(const bf16x8*)&lB[(nt * 16 + (l & 15)) * PBK + slotA];
        acc[nt] = mfma16(af, bf, acc[nt]);
      }
    }
  }
#pragma unroll
  for (int nt = 0; nt < 4; ++nt) {
    int col = nt * 16 + (l & 15);
    float bb = bias ? bias[col] : 0.f;
#pragma unroll
    for (int r = 0; r < 4; ++r) {
      long row = m0 + w * 16 + (l >> 4) * 4 + r;
      C[row * 64 + col] = f2b(acc[nt][r] + bb);
    }
  }
}

// ---------------------------------------------------------------------------
// k_prep (identical to round 0)
// ---------------------------------------------------------------------------
__global__ __launch_bounds__(256, 2) void k_prep(
    const u16* __restrict__ xb, const u16* __restrict__ Wvb, const float* __restrict__ bv,
    const u16* __restrict__ Wnb, const u16* __restrict__ WoT,
    const float* __restrict__ bo, const float* __restrict__ bn,
    u16* __restrict__ V, u16* __restrict__ Wm, float* __restrict__ biasTot) {
  __shared__ __align__(16) u16 lA[64 * PBK];
  __shared__ __align__(16) u16 lB[64 * PBK];
  const int bid = blockIdx.x;
  if (bid < 128) {
    gemm_n64(xb, Wvb, V, bv, (long)bid * 64, lA, lB);
  } else if (bid < 192) {
    gemm_n64(Wnb, WoT, Wm, nullptr, (long)(bid - 128) * 64, lA, lB);
  } else {
    const int w = threadIdx.x >> 6, l = threadIdx.x & 63;
    const int n = (bid - 192) * 4 + w;
    float s = 0.f;
#pragma unroll
    for (int j = 0; j < 8; ++j) {
      int off = (j * 64 + l) * 8;
      u16x8 a = *(const u16x8*)&Wnb[(size_t)n * 4096 + off];
      f32x4 c0 = *(const f32x4*)&bo[off];
      f32x4 c1 = *(const f32x4*)&bo[off + 4];
#pragma unroll
      for (int e = 0; e < 4; ++e) s += b2f(a[e]) * c0[e] + b2f(a[4 + e]) * c1[e];
    }
#pragma unroll
    for (int o = 32; o > 0; o >>= 1) s += __shfl_xor(s, o, 64);
    if (l == 0) biasTot[n] = s + bn[n];
  }
}

// ---------------------------------------------------------------------------
// k_main (round-0 EXACT, proven 268.6us): BK=64, XOR-swizzled LDS slots,
//   65 iters (64 X/Wn + 1 V/Wm tail), 128x128 tile, 4 waves 2x2, gl_lds16
//   staging, fp32 out via per-wave LDS transpose. LDS 32 KB. Plain mapping
//   (mapping experiments closed: m-chunk flat, n-outer -27%).
// ---------------------------------------------------------------------------
__global__ __launch_bounds__(256, 2) void k_main(
    const u16* __restrict__ X, const u16* __restrict__ Wn,
    const u16* __restrict__ V, const u16* __restrict__ Wm,
    const float* __restrict__ biasTot, float* __restrict__ Out) {
  __shared__ __align__(16) u16 smem[2 * 128 * 64];  // 32 KB
  u16* lA = smem;
  u16* lB = smem + 128 * 64;
  const int tid = threadIdx.x;
  const int w = tid >> 6, l = tid & 63;
  const int wRow = (w & 1) * 64, wCol = (w >> 1) * 64;
  const long mBase = (long)(blockIdx.x >> 5) * 128;
  const int nBase = (int)(blockIdx.x & 31) * 128;

  f32x4 acc[4][4];
#pragma unroll
  for (int mt = 0; mt < 4; ++mt)
#pragma unroll
    for (int nt = 0; nt < 4; ++nt) acc[mt][nt] = (f32x4)(0.f);

  const int srow = l >> 3;              // staging sub-row 0..7
  const int sp = ((l & 7) ^ srow) * 8;  // swizzled global 16B-slot (elements)

  for (int kb = 0; kb < 65; ++kb) {
    const u16 *pA, *pB; long lda;
    if (kb < 64) { pA = X + (long)kb * 64; pB = Wn + (long)kb * 64; lda = 4096; }
    else         { pA = V;                 pB = Wm;                 lda = 64;  }
    __syncthreads();
#pragma unroll
    for (int i = 0; i < 4; ++i) {
      int row = w * 32 + i * 8 + srow;
      gl_lds16(pA + (mBase + row) * lda + sp, lA + (w * 32 + i * 8) * 64);
      gl_lds16(pB + (long)(nBase + row) * lda + sp, lB + (w * 32 + i * 8) * 64);
    }
    __syncthreads();
#pragma unroll
    for (int kk = 0; kk < 2; ++kk) {
      int slot = ((kk * 4 + (l >> 4)) ^ (l & 7)) * 8;
      bf16x8 af[4], bfr[4];
#pragma unroll
      for (int mt = 0; mt < 4; ++mt)
        af[mt] = *(const bf16x8*)&lA[(wRow + mt * 16 + (l & 15)) * 64 + slot];
#pragma unroll
      for (int nt = 0; nt < 4; ++nt)
        bfr[nt] = *(const bf16x8*)&lB[(wCol + nt * 16 + (l & 15)) * 64 + slot];
#pragma unroll
      for (int mt = 0; mt < 4; ++mt)
#pragma unroll
        for (int nt = 0; nt < 4; ++nt) acc[mt][nt] = mfma16(af[mt], bfr[nt], acc[mt][nt]);
    }
  }

  // epilogue: bias + relu, fp32; per-wave LDS transpose (4 KB/wave), dwordx4 stores
  __syncthreads();
  float* eb = ((float*)smem) + w * 1024;
#pragma unroll
  for (int mt = 0; mt < 4; ++mt) {
#pragma unroll
    for (int nt = 0; nt < 4; ++nt) {
      float bt = biasTot[nBase + wCol + nt * 16 + (l & 15)];
#pragma unroll
      for (int r = 0; r < 4; ++r) {
        float val = acc[mt][nt][r] + bt;
        eb[((l >> 4) * 4 + r) * 64 + nt * 16 + (l & 15)] = fmaxf(val, 0.f);
      }
    }
    int rr = l >> 2, c0 = (l & 3) * 16;
    long grow = mBase + wRow + mt * 16 + rr;
    int gcol = nBase + wCol + c0;
    f32x4 o0 = *(const f32x4*)&eb[rr * 64 + c0];
    f32x4 o1 = *(const f32x4*)&eb[rr * 64 + c0 + 4];
    f32x4 o2 = *(const f32x4*)&eb[rr * 64 + c0 + 8];
    f32x4 o3 = *(const f32x4*)&eb[rr * 64 + c0 + 12];
    *(f32x4*)&Out[grow * 4096 + gcol] = o0;
    *(f32x4*)&Out[grow * 4096 + gcol + 4] = o1;
    *(f32x4*)&Out[grow * 4096 + gcol + 8] = o2;
    *(f32x4*)&Out[grow * 4096 + gcol + 12] = o3;
  }
}

// ---------------------------------------------------------------------------
extern "C" void kernel_launch(void* const* d_in, const int* in_sizes, int n_in,
                              void* d_out, int out_size, void* d_ws, size_t ws_size,
                              hipStream_t stream) {
  const float* x  = (const float*)d_in[0];
  const float* Wv = (const float*)d_in[5];
  const float* bv = (const float*)d_in[6];
  const float* Wo = (const float*)d_in[7];
  const float* bo = (const float*)d_in[8];
  const float* Wn = (const float*)d_in[9];
  const float* bn = (const float*)d_in[10];
  float* out = (float*)d_out;

  char* ws = (char*)d_ws;
  u16* xb  = (u16*)ws;                             // 8192*4096*2 = 64 MB
  u16* Wnb = (u16*)(ws + (64L << 20));             // 4096*4096*2 = 32 MB
  u16* Wvb = (u16*)(ws + (96L << 20));             // 64*4096*2   = 512 KB
  u16* WoT = (u16*)(ws + (96L << 20) + (512 << 10));   // 512 KB
  u16* V   = (u16*)(ws + (97L << 20));             // 8192*64*2   = 1 MB
  u16* Wm  = (u16*)(ws + (98L << 20));             // 4096*64*2   = 512 KB
  float* biasTot = (float*)(ws + (98L << 20) + (512 << 10));  // 16 KB

  k_cvt<<<dim3(2112), dim3(256), 0, stream>>>(x, Wn, Wv, Wo, xb, Wnb, Wvb, WoT);
  k_prep<<<dim3(1216), dim3(256), 0, stream>>>(xb, Wvb, bv, Wnb, WoT, bo, bn, V, Wm, biasTot);
  k_main<<<dim3(2048), dim3(256), 0, stream>>>(xb, Wnb, V, Wm, biasTot, out);
}

// Round 9
// 589.209 us; speedup vs baseline: 1.1857x; 1.0331x over previous
//
#include <hip/hip_runtime.h>
#include <stdint.h>

// Problem (fp32 in / fp32 out): out = relu((x + (x@Wv^T+bv)@Wo^T + bo) @ Wn^T + bn)
//   softmax over a single score == 1 -> q,k path is dead code.
// Reformulated: out = relu(x@Wn^T + v@Wm^T + biasTot)
//   v  = x@Wv^T + bv          [8192 x 64]
//   Wm = Wn @ Wo              [4096 x 64]
//   biasTot = bn + Wn @ bo    [4096]
// Round 13: RESUBMIT of round-12 (two consecutive container-infra failures
//   with DIFFERENT sources + round-3/4 precedent => flake, not kernel).
//   Full audit: no divergent sync, no OOB, swizzle verified both-sides,
//   ~200 VGPR < 256 cap, 48KB LDS -> 2 blocks/CU.
// Design: LDS-throughput fix inside round-0's proven sync.
//   k_main: 256x128 tile, 256 thr / 4 waves (2Mx2N), per-wave 128x64 out
//   (acc[8][4]) -> 24 ds_read_b128 per 64 MFMA (0.375 vs round-0's 0.5),
//   flipping the kernel from LDS-read-bound (49% MfmaUtil ceiling) to
//   MFMA-bound. Single-buffered 48KB LDS, stage->sync->compute->sync exactly
//   as round-0; 2 blocks/CU co-resident keeps inter-block overlap hiding the
//   barrier drain. Grid 1024, plain map.
// Aux = round-10 (k_cvt+kT fused grid-stride; k_prep round-0).

typedef unsigned short u16;
typedef float f32x4 __attribute__((ext_vector_type(4)));
typedef __bf16 bf16x8 __attribute__((ext_vector_type(8)));
typedef u16 u16x8 __attribute__((ext_vector_type(8)));

__device__ __forceinline__ float b2f(u16 u) {
  union { unsigned int i; float f; } x; x.i = ((unsigned int)u) << 16; return x.f;
}
__device__ __forceinline__ u16 f2b(float f) {  // round-to-nearest-even
  union { float f; unsigned int i; } x; x.f = f;
  unsigned int r = x.i + 0x7FFFu + ((x.i >> 16) & 1u);
  return (u16)(r >> 16);
}

// async global->LDS, 16B per lane; lds base wave-uniform (lane lands at base + lane*16B)
__device__ __forceinline__ void gl_lds16(const u16* g, u16* l) {
#if __has_builtin(__builtin_amdgcn_global_load_lds)
  __builtin_amdgcn_global_load_lds((__attribute__((address_space(1))) void*)g,
                                   (__attribute__((address_space(3))) void*)l, 16, 0, 0);
#else
  int lane = threadIdx.x & 63;
  *(u16x8*)(l + lane * 8) = *(const u16x8*)g;
#endif
}

__device__ __forceinline__ f32x4 mfma16(bf16x8 a, bf16x8 b, f32x4 c) {
  return __builtin_amdgcn_mfma_f32_16x16x32_bf16(a, b, c, 0, 0, 0);
}

// ---------------------------------------------------------------------------
// k_cvt: blocks [0,64):   WoT[a][k] = bf16(Wo[k][a])  (kT body, round-0)
//        blocks [64,2112): grid-stride fp32->bf16 cvt for x, Wn, Wv
// ---------------------------------------------------------------------------
#define XCH 4194304L   // 33554432/8  (x 8-elem groups)
#define WNCH 2097152L  // 16777216/8  (Wn groups)
#define TOTG 6324224L  // + 32768 Wv groups
__global__ __launch_bounds__(256) void k_cvt(
    const float* __restrict__ x, const float* __restrict__ Wn,
    const float* __restrict__ Wv, const float* __restrict__ Wo,
    u16* __restrict__ xb, u16* __restrict__ Wnb, u16* __restrict__ Wvb,
    u16* __restrict__ WoT) {
  __shared__ __align__(16) u16 t[64 * 72];
  if (blockIdx.x < 64) {
    const int b = blockIdx.x;
    const int tid = threadIdx.x;
    {
      int k = tid >> 2, a0 = (tid & 3) * 16;
      const float* src = &Wo[(size_t)(b * 64 + k) * 64 + a0];
#pragma unroll
      for (int q = 0; q < 4; ++q) {
        f32x4 v = *(const f32x4*)&src[q * 4];
#pragma unroll
        for (int e = 0; e < 4; ++e) t[k * 72 + a0 + q * 4 + e] = f2b(v[e]);
      }
    }
    __syncthreads();
    {
      int a = tid >> 2, k0 = (tid & 3) * 16;
      u16x8 o0, o1;
#pragma unroll
      for (int j = 0; j < 8; ++j) o0[j] = t[(k0 + j) * 72 + a];
#pragma unroll
      for (int j = 0; j < 8; ++j) o1[j] = t[(k0 + 8 + j) * 72 + a];
      *(u16x8*)&WoT[(size_t)a * 4096 + b * 64 + k0] = o0;
      *(u16x8*)&WoT[(size_t)a * 4096 + b * 64 + k0 + 8] = o1;
    }
    return;
  }
  long i = (long)(blockIdx.x - 64) * 256 + threadIdx.x;
  const long stride = 2048L * 256;
  for (; i < TOTG; i += stride) {
    const float* src; u16* dst; long off;
    if (i < XCH) { src = x; dst = xb; off = i * 8; }
    else if (i < XCH + WNCH) { src = Wn; dst = Wnb; off = (i - XCH) * 8; }
    else { src = Wv; dst = Wvb; off = (i - XCH - WNCH) * 8; }
    f32x4 a = *(const f32x4*)&src[off];
    f32x4 b = *(const f32x4*)&src[off + 4];
    u16x8 o;
#pragma unroll
    for (int e = 0; e < 4; ++e) { o[e] = f2b(a[e]); o[4 + e] = f2b(b[e]); }
    *(u16x8*)&dst[off] = o;
  }
}

// ---------------------------------------------------------------------------
// gemm_n64 (identical to round 0)
// ---------------------------------------------------------------------------
#define PBK 128
__device__ void gemm_n64(const u16* __restrict__ A, const u16* __restrict__ B,
                         u16* __restrict__ C, const float* __restrict__ bias,
                         long m0, u16* lA, u16* lB) {
  const int tid = threadIdx.x;
  const int w = tid >> 6, l = tid & 63;
  f32x4 acc[4];
#pragma unroll
  for (int nt = 0; nt < 4; ++nt) acc[nt] = (f32x4)(0.f);

  for (int k0 = 0; k0 < 4096; k0 += PBK) {
    __syncthreads();
#pragma unroll
    for (int i = 0; i < 4; ++i) {
      int row = w * 16 + i * 4 + (l >> 4);
      int p = (l & 15) ^ (i * 4 + (l >> 4));
      gl_lds16(A + (m0 + row) * (long)4096 + k0 + p * 8, lA + (w * 16 + i * 4) * PBK);
      gl_lds16(B + (long)row * 4096 + k0 + p * 8, lB + (w * 16 + i * 4) * PBK);
    }
    __syncthreads();
#pragma unroll
    for (int kk = 0; kk < 4; ++kk) {
      int slotA = ((kk * 4 + (l >> 4)) ^ (l & 15)) * 8;
      bf16x8 af = *(const bf16x8*)&lA[(w * 16 + (l & 15)) * PBK + slotA];
#pragma unroll
      for (int nt = 0; nt < 4; ++nt) {
        bf16x8 bf = *(const bf16x8*)&lB[(nt * 16 + (l & 15)) * PBK + slotA];
        acc[nt] = mfma16(af, bf, acc[nt]);
      }
    }
  }
#pragma unroll
  for (int nt = 0; nt < 4; ++nt) {
    int col = nt * 16 + (l & 15);
    float bb = bias ? bias[col] : 0.f;
#pragma unroll
    for (int r = 0; r < 4; ++r) {
      long row = m0 + w * 16 + (l >> 4) * 4 + r;
      C[row * 64 + col] = f2b(acc[nt][r] + bb);
    }
  }
}

// ---------------------------------------------------------------------------
// k_prep (identical to round 0)
// ---------------------------------------------------------------------------
__global__ __launch_bounds__(256, 2) void k_prep(
    const u16* __restrict__ xb, const u16* __restrict__ Wvb, const float* __restrict__ bv,
    const u16* __restrict__ Wnb, const u16* __restrict__ WoT,
    const float* __restrict__ bo, const float* __restrict__ bn,
    u16* __restrict__ V, u16* __restrict__ Wm, float* __restrict__ biasTot) {
  __shared__ __align__(16) u16 lA[64 * PBK];
  __shared__ __align__(16) u16 lB[64 * PBK];
  const int bid = blockIdx.x;
  if (bid < 128) {
    gemm_n64(xb, Wvb, V, bv, (long)bid * 64, lA, lB);
  } else if (bid < 192) {
    gemm_n64(Wnb, WoT, Wm, nullptr, (long)(bid - 128) * 64, lA, lB);
  } else {
    const int w = threadIdx.x >> 6, l = threadIdx.x & 63;
    const int n = (bid - 192) * 4 + w;
    float s = 0.f;
#pragma unroll
    for (int j = 0; j < 8; ++j) {
      int off = (j * 64 + l) * 8;
      u16x8 a = *(const u16x8*)&Wnb[(size_t)n * 4096 + off];
      f32x4 c0 = *(const f32x4*)&bo[off];
      f32x4 c1 = *(const f32x4*)&bo[off + 4];
#pragma unroll
      for (int e = 0; e < 4; ++e) s += b2f(a[e]) * c0[e] + b2f(a[4 + e]) * c1[e];
    }
#pragma unroll
    for (int o = 32; o > 0; o >>= 1) s += __shfl_xor(s, o, 64);
    if (l == 0) biasTot[n] = s + bn[n];
  }
}

// ---------------------------------------------------------------------------
// k_main (ROUND-12 design): 256x128 tile, 256 thr / 4 waves (wm=w>>1, wn=w&1),
//   per-wave 128x64 out = acc[8][4]. BK=64. Round-0 sync semantics EXACTLY:
//   per K-tile { __syncthreads; 12x gl_lds16 (single buffer); __syncthreads
//   (compiler drains vmcnt before s_barrier -> staging complete); 2x
//   (12 ds_read_b128 + 32 MFMA) }.
// LDS 48KB: A rows 0..255 at [0,16384) elems, B rows 0..127 at [16384,24576).
//   Row = 64 elems (128B, 8 x 16B slots). LDS[r][s] = global[r][s ^ (r&7)]:
//   stage op covers 32 rows; wave w rows op*32+w*8+(l>>3), pre-swizzled
//   global slot ((l&7)^(l>>3))*8, LDS base op*2048 + w*512 (+lane*16B auto).
//   Read: row ...+frow (frow=l&15), LDS slot ((kk*4+(l>>4)) ^ (l&7)) -> same
//   2-way-free bank pattern as round-0.
//   Tiles 0..63 = X/Wn (k-off kb*64, lda 4096); tile 64 = V/Wm (lda 64).
// ---------------------------------------------------------------------------
__global__ __launch_bounds__(256, 2) void k_main(
    const u16* __restrict__ X, const u16* __restrict__ Wn,
    const u16* __restrict__ V, const u16* __restrict__ Wm,
    const float* __restrict__ biasTot, float* __restrict__ Out) {
  __shared__ __align__(16) u16 smem[24576];  // 48 KB
  const int tid = threadIdx.x;
  const int w = tid >> 6, l = tid & 63;
  const int wm = w >> 1, wn = w & 1;
  const long mBase = (long)(blockIdx.x >> 5) * 256;
  const int  nBase = (int)(blockIdx.x & 31) * 128;

  // staging constants
  const int rsub = w * 8 + (l >> 3);           // row within 32-row op (0..31)
  const int swe  = ((l & 7) ^ (l >> 3)) * 8;   // pre-swizzled global slot (elems)
  const int ldsS = w * 512;                    // wave base within op (elems)

  // fragment-read constants
  const int frow = l & 15, fsl = l >> 4, fx = l & 7;
  const int sl0 = (fsl ^ fx) * 8;              // kk0 swizzled slot (elems)
  const int sl1 = ((4 + fsl) ^ fx) * 8;        // kk1
  const int aB = wm * 8192 + frow * 64;        // + mt*1024
  const int bB = 16384 + wn * 4096 + frow * 64;  // + nt*1024

  f32x4 acc[8][4];
#pragma unroll
  for (int mt = 0; mt < 8; ++mt)
#pragma unroll
    for (int nt = 0; nt < 4; ++nt) acc[mt][nt] = (f32x4)(0.f);

  for (int kb = 0; kb < 65; ++kb) {
    const u16 *pA, *pB; long lda, ko;
    if (kb < 64) { pA = X; pB = Wn; lda = 4096; ko = (long)kb * 64; }
    else         { pA = V; pB = Wm; lda = 64;   ko = 0; }
    __syncthreads();
#pragma unroll
    for (int op = 0; op < 8; ++op)   // A: 256 rows
      gl_lds16(pA + (mBase + op * 32 + rsub) * lda + ko + swe,
               smem + op * 2048 + ldsS);
#pragma unroll
    for (int op = 0; op < 4; ++op)   // B: 128 rows
      gl_lds16(pB + ((long)nBase + op * 32 + rsub) * lda + ko + swe,
               smem + 16384 + op * 2048 + ldsS);
    __syncthreads();
#pragma unroll
    for (int kk = 0; kk < 2; ++kk) {
      const int sl = kk ? sl1 : sl0;
      bf16x8 af[8], bf[4];
#pragma unroll
      for (int mt = 0; mt < 8; ++mt)
        af[mt] = *(const bf16x8*)&smem[aB + mt * 1024 + sl];
#pragma unroll
      for (int nt = 0; nt < 4; ++nt)
        bf[nt] = *(const bf16x8*)&smem[bB + nt * 1024 + sl];
      __builtin_amdgcn_s_setprio(1);
#pragma unroll
      for (int mt = 0; mt < 8; ++mt)
#pragma unroll
        for (int nt = 0; nt < 4; ++nt)
          acc[mt][nt] = mfma16(af[mt], bf[nt], acc[mt][nt]);
      __builtin_amdgcn_s_setprio(0);
    }
  }

  // epilogue: bias + relu, fp32; per-wave LDS transpose (4 KB/wave)
  __syncthreads();
  float* eb = ((float*)smem) + w * 1024;
  float bt[4];
#pragma unroll
  for (int nt = 0; nt < 4; ++nt) bt[nt] = biasTot[nBase + wn * 64 + nt * 16 + frow];
#pragma unroll
  for (int mt = 0; mt < 8; ++mt) {
#pragma unroll
    for (int nt = 0; nt < 4; ++nt) {
#pragma unroll
      for (int r = 0; r < 4; ++r) {
        float val = acc[mt][nt][r] + bt[nt];
        eb[(fsl * 4 + r) * 64 + nt * 16 + frow] = fmaxf(val, 0.f);
      }
    }
    int rr = l >> 2, c0 = (l & 3) * 16;
    long grow = mBase + wm * 128 + mt * 16 + rr;
    int gcol = nBase + wn * 64 + c0;
    f32x4 o0 = *(const f32x4*)&eb[rr * 64 + c0];
    f32x4 o1 = *(const f32x4*)&eb[rr * 64 + c0 + 4];
    f32x4 o2 = *(const f32x4*)&eb[rr * 64 + c0 + 8];
    f32x4 o3 = *(const f32x4*)&eb[rr * 64 + c0 + 12];
    *(f32x4*)&Out[grow * 4096 + gcol] = o0;
    *(f32x4*)&Out[grow * 4096 + gcol + 4] = o1;
    *(f32x4*)&Out[grow * 4096 + gcol + 8] = o2;
    *(f32x4*)&Out[grow * 4096 + gcol + 12] = o3;
  }
}

// ---------------------------------------------------------------------------
extern "C" void kernel_launch(void* const* d_in, const int* in_sizes, int n_in,
                              void* d_out, int out_size, void* d_ws, size_t ws_size,
                              hipStream_t stream) {
  const float* x  = (const float*)d_in[0];
  const float* Wv = (const float*)d_in[5];
  const float* bv = (const float*)d_in[6];
  const float* Wo = (const float*)d_in[7];
  const float* bo = (const float*)d_in[8];
  const float* Wn = (const float*)d_in[9];
  const float* bn = (const float*)d_in[10];
  float* out = (float*)d_out;

  char* ws = (char*)d_ws;
  u16* xb  = (u16*)ws;                             // 8192*4096*2 = 64 MB
  u16* Wnb = (u16*)(ws + (64L << 20));             // 4096*4096*2 = 32 MB
  u16* Wvb = (u16*)(ws + (96L << 20));             // 64*4096*2   = 512 KB
  u16* WoT = (u16*)(ws + (96L << 20) + (512 << 10));   // 512 KB
  u16* V   = (u16*)(ws + (97L << 20));             // 8192*64*2   = 1 MB
  u16* Wm  = (u16*)(ws + (98L << 20));             // 4096*64*2   = 512 KB
  float* biasTot = (float*)(ws + (98L << 20) + (512 << 10));  // 16 KB

  k_cvt<<<dim3(2112), dim3(256), 0, stream>>>(x, Wn, Wv, Wo, xb, Wnb, Wvb, WoT);
  k_prep<<<dim3(1216), dim3(256), 0, stream>>>(xb, Wvb, bv, Wnb, WoT, bo, bn, V, Wm, biasTot);
  k_main<<<dim3(1024), dim3(256), 0, stream>>>(xb, Wnb, V, Wm, biasTot, out);
}